// Round 2
// baseline (514.515 us; speedup 1.0000x reference)
//
#include <hip/hip_runtime.h>

// Problem constants (from reference): N=128, Cin=64, T=128, V=25, O=64, R=8
#define EPSV 1e-5f
constexpr int NN = 128, CIN = 64, TT = 128, VV = 25, OO = 64, RR = 8;
constexpr int TVQ   = TT * VV;        // 3200  (per-channel plane)
constexpr int XSAMP = CIN * TVQ;      // 204800 (per-sample x)
constexpr int YSAMP = OO * TT * VV;   // 819200 (per-sample y)
constexpr int RTV   = RR * TT * VV;   // 25600 (GroupNorm count)
constexpr int S12N  = 2 * RR * VV;    // 400   (s1+s2 per sample)
constexpr int YPAD  = 28;             // padded v for 16B-aligned y_sum rows
constexpr int YSUMP_SAMP = OO * VV * YPAD;  // 44800

// ---------------------------------------------------------------- zero scratch
__global__ __launch_bounds__(256) void kZero(float* __restrict__ p, int n)
{
    int i = blockIdx.x * 256 + threadIdx.x;
    if (i < n) p[i] = 0.f;
}

// ---------------------------------------------------------------- kernel A
// One pass over x. Per block: (n, t-chunk of 32). 200 threads own 4 consecutive
// (t,v) points each (float4 loads, perfectly coalesced). Each thread keeps the
// 8 conv1 + 8 conv2 channel accumulators per point in registers across the
// c-loop. Outputs: s12g[n][400] = sum_t conv_pre_bias (branch1 then branch2),
// ssqg[n][2] = sum of squared conv outputs (bias included).
__global__ __launch_bounds__(256) void kA(const float* __restrict__ x,
    const float* __restrict__ w1, const float* __restrict__ b1,
    const float* __restrict__ w2, const float* __restrict__ b2,
    float* __restrict__ s12g, float* __restrict__ ssqg)
{
    __shared__ float wt1[CIN * RR], wt2[CIN * RR];   // transposed [c][r]
    __shared__ float s1l[RR * VV], s2l[RR * VV];
    __shared__ float redA[4], redB[4];
    const int tid = threadIdx.x;
    const int tc  = blockIdx.x;   // 0..3  (32 t each)
    const int n   = blockIdx.y;

    for (int e = tid; e < CIN * RR; e += 256) {
        int r = e >> 6, c = e & 63;
        wt1[c * RR + r] = w1[e];
        wt2[c * RR + r] = w2[e];
    }
    for (int e = tid; e < 2 * RR * VV; e += 256) {
        if (e < RR * VV) s1l[e] = 0.f; else s2l[e - RR * VV] = 0.f;
    }
    __syncthreads();

    float acc1[4][RR], acc2[4][RR];
    #pragma unroll
    for (int j = 0; j < 4; ++j)
        #pragma unroll
        for (int r = 0; r < RR; ++r) { acc1[j][r] = 0.f; acc2[j][r] = 0.f; }

    const bool active = (tid < 200);
    const int p0 = tid * 4;                       // flat (t,v) offset in chunk
    const float* xb = x + (size_t)n * XSAMP + tc * 800 + p0;
    if (active) {
        #pragma unroll 4
        for (int c = 0; c < CIN; ++c) {
            float4 xv  = *(const float4*)(xb + c * TVQ);
            float4 wa1 = *(const float4*)(&wt1[c * RR]);
            float4 wb1 = *(const float4*)(&wt1[c * RR + 4]);
            float4 wa2 = *(const float4*)(&wt2[c * RR]);
            float4 wb2 = *(const float4*)(&wt2[c * RR + 4]);
            float xj[4]  = {xv.x, xv.y, xv.z, xv.w};
            float w1v[8] = {wa1.x, wa1.y, wa1.z, wa1.w, wb1.x, wb1.y, wb1.z, wb1.w};
            float w2v[8] = {wa2.x, wa2.y, wa2.z, wa2.w, wb2.x, wb2.y, wb2.z, wb2.w};
            #pragma unroll
            for (int j = 0; j < 4; ++j)
                #pragma unroll
                for (int r = 0; r < RR; ++r) {
                    acc1[j][r] += w1v[r] * xj[j];
                    acc2[j][r] += w2v[r] * xj[j];
                }
        }
    }

    float b1r[RR], b2r[RR];
    #pragma unroll
    for (int r = 0; r < RR; ++r) { b1r[r] = b1[r]; b2r[r] = b2[r]; }

    float ssq1 = 0.f, ssq2 = 0.f;
    if (active) {
        #pragma unroll
        for (int j = 0; j < 4; ++j) {
            int v = (p0 + j) % VV;
            #pragma unroll
            for (int r = 0; r < RR; ++r) {
                float c1 = acc1[j][r] + b1r[r]; ssq1 += c1 * c1;
                float c2 = acc2[j][r] + b2r[r]; ssq2 += c2 * c2;
                atomicAdd(&s1l[r * VV + v], acc1[j][r]);
                atomicAdd(&s2l[r * VV + v], acc2[j][r]);
            }
        }
    }
    #pragma unroll
    for (int off = 32; off > 0; off >>= 1) {
        ssq1 += __shfl_down(ssq1, off);
        ssq2 += __shfl_down(ssq2, off);
    }
    __syncthreads();                               // LDS atomics complete
    // BUGFIX R1: 400 entries, 256 threads -> must loop (was `if (tid < 400)`,
    // which silently dropped entries 256..399 = most of branch 2)
    for (int e = tid; e < S12N; e += 256) {
        float pv = (e < RR * VV) ? s1l[e] : s2l[e - RR * VV];
        atomicAdd(&s12g[n * S12N + e], pv);
    }
    if ((tid & 63) == 0) { redA[tid >> 6] = ssq1; redB[tid >> 6] = ssq2; }
    __syncthreads();
    if (tid == 0) {
        atomicAdd(&ssqg[n * 2 + 0], redA[0] + redA[1] + redA[2] + redA[3]);
        atomicAdd(&ssqg[n * 2 + 1], redB[0] + redB[1] + redB[2] + redB[3]);
    }
}

// ---------------------------------------------------------------- kernel B
__device__ __forceinline__ float tanh_fast(float v)
{
    float e = __expf(2.f * v);
    return 1.f - 2.f / (e + 1.f);    // safe at +/-inf of e
}

// One block per sample, 512 threads (BUGFIX R1: was 256, so `tid < 400` paths
// missed entries 256..399). Finalizes GN stats, builds normalized temporal
// means x1g/x2g [8][25], then ys = tanh(diff)+tanh(prod)+A, folds w4/b4 into
// padded y_sum[n][o][u][28] (pad zeroed).
__global__ __launch_bounds__(512) void kB(
    const float* __restrict__ s12g, const float* __restrict__ ssqg,
    const float* __restrict__ b1, const float* __restrict__ g1, const float* __restrict__ be1,
    const float* __restrict__ b2, const float* __restrict__ g2, const float* __restrict__ be2,
    const float* __restrict__ Amat, const float* __restrict__ w4, const float* __restrict__ b4,
    float* __restrict__ ysump)
{
    __shared__ float x1g[RR * VV], x2g[RR * VV];
    __shared__ float w4l[OO * RR];
    __shared__ float stats[2];
    __shared__ float mss[4];       // mu1, rs1, mu2, rs2
    const int tid = threadIdx.x;
    const int n   = blockIdx.x;

    if (tid < 2) stats[tid] = 0.f;
    for (int e = tid; e < OO * RR; e += 512) w4l[e] = w4[e];
    __syncthreads();

    float sv = 0.f;
    if (tid < S12N) {                      // 400 < 512: covers all entries now
        sv = s12g[n * S12N + tid];
        atomicAdd(&stats[tid / (RR * VV)], sv);
    }
    __syncthreads();
    if (tid == 0) {
        float sb1 = 0.f, sb2 = 0.f;
        for (int r = 0; r < RR; ++r) { sb1 += b1[r]; sb2 += b2[r]; }
        float mu1 = (stats[0] + (float)(TT * VV) * sb1) / (float)RTV;
        float mu2 = (stats[1] + (float)(TT * VV) * sb2) / (float)RTV;
        float var1 = ssqg[n * 2 + 0] / (float)RTV - mu1 * mu1;
        float var2 = ssqg[n * 2 + 1] / (float)RTV - mu2 * mu2;
        mss[0] = mu1; mss[1] = rsqrtf(var1 + EPSV);
        mss[2] = mu2; mss[3] = rsqrtf(var2 + EPSV);
    }
    __syncthreads();
    if (tid < S12N) {
        int br = tid / (RR * VV);
        int i  = tid % (RR * VV);
        int r  = i / VV;
        float mu = mss[br * 2], rs = mss[br * 2 + 1];
        float mean_t = sv / (float)TT + (br ? b2[r] : b1[r]);
        float g  = br ? g2[r]  : g1[r];
        float be = br ? be2[r] : be1[r];
        float val = g * (mean_t - mu) * rs + be;
        if (br == 0) x1g[i] = val; else x2g[i] = val;
    }
    __syncthreads();

    float* yn = ysump + (size_t)n * YSUMP_SAMP;
    for (int p = tid; p < VV * VV; p += 512) {
        int u = p / VV, v = p % VV;
        float Av = Amat[p];
        float ys[RR];
        #pragma unroll
        for (int r = 0; r < RR; ++r) {
            float d = x1g[r * VV + u] - x1g[r * VV + v];
            float m = x2g[r * VV + u] * x2g[r * VV + v];
            ys[r] = tanh_fast(d) + tanh_fast(m) + Av;   // ALPHA = 1
        }
        for (int o = 0; o < OO; ++o) {
            float a = b4[o];
            #pragma unroll
            for (int r = 0; r < RR; ++r) a += w4l[o * RR + r] * ys[r];
            yn[(o * VV + u) * YPAD + v] = a;
        }
    }
    // zero the v-pad cells (25..27)
    for (int q = tid; q < OO * VV * 3; q += 512) {
        int o = q / (VV * 3), rem = q % (VV * 3);
        int u = rem / 3, v = VV + rem % 3;
        yn[(o * VV + u) * YPAD + v] = 0.f;
    }
}

// ---------------------------------------------------------------- kernel C
// Fused conv3 + vertex aggregation. Block = (n, t-chunk of 8), 512 threads =
// 64 o x 8 t. x tile [64c][8t][28pad] in LDS (all lanes same address ->
// broadcast); w3 row in 32-reg halves; x3[o,t,:] lives in 25 registers; per-u
// y_sum rows staged into LDS (stride 29, conflict-free) so the 8 t-threads
// per o share one global read; results transposed through LDS for coalesced
// float4 stores.
__global__ __launch_bounds__(512, 4) void kC(
    const float* __restrict__ x, const float* __restrict__ w3,
    const float* __restrict__ b3, const float* __restrict__ ysump,
    float* __restrict__ y)
{
    __shared__ float xl[CIN * 8 * 28];   // 14336 floats = 57344 B
    __shared__ float ysl[OO * 29];       //  1856 floats =  7424 B
    const int tid = threadIdx.x;
    const int o   = tid & 63;
    const int th  = tid >> 6;            // 0..7 (local t)
    const int tc  = blockIdx.x;          // 0..15
    const int n   = blockIdx.y;
    const int t0  = tc * 8;

    // stage x[n, :, t0:t0+8, :]  (coalesced scalar loads)
    const float* xn = x + (size_t)n * XSAMP + t0 * VV;
    for (int e = tid; e < CIN * 8 * VV; e += 512) {
        int c = e / 200, rem = e % 200;
        int t = rem / VV, v = rem % VV;
        xl[c * 224 + t * 28 + v] = xn[c * TVQ + rem];
    }
    __syncthreads();

    float acc[VV];
    #pragma unroll
    for (int i = 0; i < VV; ++i) acc[i] = 0.f;

    #pragma unroll 1
    for (int half = 0; half < 2; ++half) {
        float w3r[32];
        #pragma unroll
        for (int q = 0; q < 8; ++q) {
            float4 wv = *(const float4*)(w3 + o * CIN + half * 32 + q * 4);
            w3r[q*4+0] = wv.x; w3r[q*4+1] = wv.y; w3r[q*4+2] = wv.z; w3r[q*4+3] = wv.w;
        }
        #pragma unroll
        for (int ci = 0; ci < 32; ++ci) {
            const float* p = &xl[(half * 32 + ci) * 224 + th * 28];
            const float w = w3r[ci];
            float4 a0 = *(const float4*)(p + 0);
            float4 a1 = *(const float4*)(p + 4);
            float4 a2 = *(const float4*)(p + 8);
            float4 a3 = *(const float4*)(p + 12);
            float4 a4 = *(const float4*)(p + 16);
            float4 a5 = *(const float4*)(p + 20);
            float  a6 = p[24];
            acc[0]  += w*a0.x; acc[1]  += w*a0.y; acc[2]  += w*a0.z; acc[3]  += w*a0.w;
            acc[4]  += w*a1.x; acc[5]  += w*a1.y; acc[6]  += w*a1.z; acc[7]  += w*a1.w;
            acc[8]  += w*a2.x; acc[9]  += w*a2.y; acc[10] += w*a2.z; acc[11] += w*a2.w;
            acc[12] += w*a3.x; acc[13] += w*a3.y; acc[14] += w*a3.z; acc[15] += w*a3.w;
            acc[16] += w*a4.x; acc[17] += w*a4.y; acc[18] += w*a4.z; acc[19] += w*a4.w;
            acc[20] += w*a5.x; acc[21] += w*a5.y; acc[22] += w*a5.z; acc[23] += w*a5.w;
            acc[24] += w*a6;
        }
    }
    const float bias = b3[o];
    #pragma unroll
    for (int i = 0; i < VV; ++i) acc[i] += bias;

    // aggregation: for each u, stage ysum[:,u,:] then dot with x3
    const float* ysn = ysump + (size_t)n * YSUMP_SAMP;
    for (int u = 0; u < VV; ++u) {
        __syncthreads();                 // protect ysl from previous iter / end C1
        for (int e = tid; e < OO * VV; e += 512) {
            int oo = e / VV, vv = e % VV;
            ysl[oo * 29 + vv] = ysn[(oo * VV + u) * YPAD + vv];
        }
        __syncthreads();
        const float* yr = &ysl[o * 29];
        float s = 0.f;
        #pragma unroll
        for (int v = 0; v < VV; ++v) s += yr[v] * acc[v];
        xl[o * 200 + th * VV + u] = s;   // result transpose buffer (xl reused)
    }
    __syncthreads();
    // coalesced write-out: per o, 200 contiguous floats -> y[n][o][t0:t0+8][:]
    float* yb = y + (size_t)n * YSAMP + t0 * VV;
    for (int idx = tid; idx < (OO * 8 * VV) / 4; idx += 512) {
        int oo = idx / 50, rem = idx % 50;
        *(float4*)(yb + oo * TVQ + rem * 4) = *(const float4*)(&xl[idx * 4]);
    }
}

// ---------------------------------------------------------------- launch
extern "C" void kernel_launch(void* const* d_in, const int* in_sizes, int n_in,
                              void* d_out, int out_size, void* d_ws, size_t ws_size,
                              hipStream_t stream)
{
    const float* x   = (const float*)d_in[0];
    const float* Am  = (const float*)d_in[1];
    const float* w1  = (const float*)d_in[2];
    const float* b1  = (const float*)d_in[3];
    const float* g1  = (const float*)d_in[4];
    const float* be1 = (const float*)d_in[5];
    const float* w2  = (const float*)d_in[6];
    const float* b2  = (const float*)d_in[7];
    const float* g2  = (const float*)d_in[8];
    const float* be2 = (const float*)d_in[9];
    const float* w3  = (const float*)d_in[10];
    const float* b3  = (const float*)d_in[11];
    const float* w4  = (const float*)d_in[12];
    const float* b4  = (const float*)d_in[13];
    float* y  = (float*)d_out;
    float* ws = (float*)d_ws;
    // workspace: s12g 128*400 | ssqg 128*2 | ysump 128*44800  (~23.1 MB total)
    float* s12g  = ws;
    float* ssqg  = ws + NN * S12N;
    float* ysump = ws + NN * S12N + NN * 2;

    const int nz = NN * S12N + NN * 2;
    hipLaunchKernelGGL(kZero, dim3((nz + 255) / 256), dim3(256), 0, stream, ws, nz);
    hipLaunchKernelGGL(kA, dim3(4, NN), dim3(256), 0, stream,
                       x, w1, b1, w2, b2, s12g, ssqg);
    hipLaunchKernelGGL(kB, dim3(NN), dim3(512), 0, stream,
                       s12g, ssqg, b1, g1, be1, b2, g2, be2, Am, w4, b4, ysump);
    hipLaunchKernelGGL(kC, dim3(16, NN), dim3(512), 0, stream,
                       x, w3, b3, ysump, y);
}